// Round 1
// 143.863 us; speedup vs baseline: 1.0339x; 1.0339x over previous
//
#include <hip/hip_runtime.h>
#include <math.h>

#define EMBED 768
#define NTOK  4096
#define NB    4
#define ROWS  16384          // 4 * 4096
#define CN    192            // Q(64)|K(64)|V(64)

typedef __attribute__((ext_vector_type(8))) short bf16x8;          // 8 bf16 = 4 VGPR
typedef __attribute__((ext_vector_type(8))) unsigned short u16x8;  // store vector
typedef __attribute__((ext_vector_type(4))) float f32x4;           // MFMA acc

// Split fp32 into h + l bf16 (RNE both): f ~= h + l, err ~2^-17 rel.
__device__ inline void split2(float f, short& h, short& l) {
  union { float f; unsigned u; } a; a.f = f;
  unsigned r = (a.u + 0x7FFFu + ((a.u >> 16) & 1u)) & 0xFFFF0000u;
  h = (short)(r >> 16);
  union { unsigned u; float f; } hf; hf.u = r;
  union { float f; unsigned u; } b; b.f = f - hf.f;
  l = (short)((b.u + 0x7FFFu + ((b.u >> 16) & 1u)) >> 16);
}

// ---------------------------------------------------------------------------
// W prep v2: LDS-staged transpose, coalesced reads AND writes.
// Output layout: Wt[ks][plane][n][k32] bf16, i.e. elem = ks*12288 + p*6144 + n*32 + kk.
//   ks = k/32 (24 steps), plane 0=high 1=low, n in [0,192) (Q|K|V), kk = k%32.
// Grid: 72 blocks (3 matrices x 24 ks), 256 threads.
// Also zeroes Vsum (replaces hipMemsetAsync).
// ---------------------------------------------------------------------------
__global__ __launch_bounds__(256) void wprep(const float* __restrict__ Wq,
                                             const float* __restrict__ Wk,
                                             const float* __restrict__ Wv,
                                             unsigned short* __restrict__ Wt,
                                             float* __restrict__ Vsum) {
  __shared__ float tile[32 * 64];   // W[ks*32 .. +32][0..64]
  const int b   = blockIdx.x;
  const int mat = b / 24;           // 0=Wq 1=Wk 2=Wv
  const int ks  = b - mat * 24;
  const float* W = (mat == 0) ? Wq : (mat == 1) ? Wk : Wv;
  const int t = threadIdx.x;

  // coalesced load: 2048 floats = 512 float4, 2 per thread
  const float4* src = (const float4*)(W + ks * 2048);
  ((float4*)tile)[t]       = src[t];
  ((float4*)tile)[t + 256] = src[t + 256];
  __syncthreads();

  // write side: thread -> (n, k-oct). 16B vector stores, k-contiguous.
  const int n  = t >> 2;            // 0..63
  const int ko = (t & 3) * 8;       // 0,8,16,24
  u16x8 hv, lv;
#pragma unroll
  for (int j = 0; j < 8; ++j) {
    short h, l;
    split2(tile[(ko + j) * 64 + n], h, l);
    hv[j] = (unsigned short)h;
    lv[j] = (unsigned short)l;
  }
  const size_t base = (size_t)ks * 12288 + (size_t)(mat * 64 + n) * 32 + ko;
  *(u16x8*)(Wt + base)        = hv;
  *(u16x8*)(Wt + base + 6144) = lv;

  if (b == 0 && t < NB * 64) Vsum[t] = 0.f;
}

// ---------------------------------------------------------------------------
// MFMA GEMM: C[16384][192] = x @ W + bias via split-bf16 (3 passes).
// 512 blocks x 256 threads (4 waves: 2m x 2n). Block tile 32x192, wave 16x96
// (m_t=1, n_t=6). 2048 waves = 2 waves/SIMD. Explicit 2-step ping-pong
// prefetch (no register copy loop), launch_bounds(256,2) -> 256 VGPR budget
// so the pipeline survives regalloc. B re-laid out k-step-major: per iter,
// 2 pointer bumps + 12 imm-offset dwordx4 loads.
// Fused Vsum epilogue (replaces vsum_kernel).
// ---------------------------------------------------------------------------
__device__ inline void cvt8(const float4 a0, const float4 a1, bf16x8& h, bf16x8& l) {
  const float f[8] = {a0.x, a0.y, a0.z, a0.w, a1.x, a1.y, a1.z, a1.w};
#pragma unroll
  for (int j = 0; j < 8; ++j) {
    union { float f; unsigned u; } a; a.f = f[j];
    unsigned th = a.u + 0x7FFFu + ((a.u >> 16) & 1u);
    h[j] = (short)(th >> 16);
    union { unsigned u; float f; } hf; hf.u = th & 0xFFFF0000u;
    union { float f; unsigned u; } r; r.f = f[j] - hf.f;
    unsigned tl = r.u + 0x7FFFu + ((r.u >> 16) & 1u);
    l[j] = (short)(tl >> 16);
  }
}

__device__ inline void loadA(const float* __restrict__ p, float4* d) {
  d[0] = *(const float4*)p;
  d[1] = *(const float4*)(p + 4);
}

__device__ inline void loadB(const unsigned short* __restrict__ p0,
                             const unsigned short* __restrict__ p1, bf16x8* d) {
#pragma unroll
  for (int nt = 0; nt < 6; ++nt) {
    d[nt]     = *(const bf16x8*)(p0 + (nt - 2) * 512);   // byte offs -2048..+3072
    d[6 + nt] = *(const bf16x8*)(p1 + (nt - 2) * 512);
  }
}

__device__ inline void compute6(const float4* A, const bf16x8* B, f32x4* acc) {
  bf16x8 ah, al;
  cvt8(A[0], A[1], ah, al);
#pragma unroll
  for (int nt = 0; nt < 6; ++nt) {
    acc[nt] = __builtin_amdgcn_mfma_f32_16x16x32_bf16(ah, B[nt],     acc[nt], 0, 0, 0);
    acc[nt] = __builtin_amdgcn_mfma_f32_16x16x32_bf16(ah, B[6 + nt], acc[nt], 0, 0, 0);
    acc[nt] = __builtin_amdgcn_mfma_f32_16x16x32_bf16(al, B[nt],     acc[nt], 0, 0, 0);
  }
}

__global__ __launch_bounds__(256, 2) void qkv_mfma(const float* __restrict__ x,
                                                   const unsigned short* __restrict__ Wtu,
                                                   const float* __restrict__ bq,
                                                   const float* __restrict__ bk,
                                                   const float* __restrict__ bv,
                                                   float* __restrict__ C,
                                                   float* __restrict__ Vsum) {
  const int lane  = threadIdx.x & 63;
  const int wm    = (threadIdx.x >> 6) & 1;  // m-half (16 rows each)
  const int wn    = threadIdx.x >> 7;        // n-half (96 cols each)
  const int ml    = lane & 15;
  const int q     = lane >> 4;
  const int r0    = blockIdx.x * 32;
  const int nbase = wn * 96;

  f32x4 acc[6] = {};

  const float* xap = x + (size_t)(r0 + wm * 16 + ml) * EMBED + q * 8;
  // B base pointers centered at nt=2: elem = (nbase + 32 + ml)*32 + q*8, plane stride 6144
  const unsigned short* b0 = Wtu + (nbase + 32 + ml) * 32 + q * 8;
  const unsigned short* b1 = b0 + 6144;

  float4 A0[2], A1[2];
  bf16x8 B0[12], B1[12];

  loadA(xap, A0);
  loadB(b0, b1, B0);
  b0 += 12288; b1 += 12288;        // -> ks=1

  for (int ks = 0; ks < 24; ks += 2) {
    // prefetch ks+1, compute ks
    loadA(xap + 32, A1);
    loadB(b0, b1, B1);
    b0 += 12288; b1 += 12288;
    compute6(A0, B0, acc);
    // prefetch ks+2, compute ks+1
    if (ks < 22) {
      loadA(xap + 64, A0);
      loadB(b0, b1, B0);
      b0 += 12288; b1 += 12288;
    }
    xap += 64;
    compute6(A1, B1, acc);
  }

  // epilogue: bias + store. C/D layout: col = ml, row = q*4 + reg.
#pragma unroll
  for (int nt = 0; nt < 6; ++nt) {
    const int n = nbase + nt * 16 + ml;
    const float bias = (n < 64) ? bq[n] : (n < 128) ? bk[n - 64] : bv[n - 128];
#pragma unroll
    for (int reg = 0; reg < 4; ++reg) {
      const int row = r0 + wm * 16 + q * 4 + reg;
      C[(size_t)row * CN + n] = acc[nt][reg] + bias;
    }
  }

  // fused Vsum partial: V cols are n >= 128 -> wn==1, nt>=2.
  // Each wn==1 wave covers 16 rows; sum over its 4 regs + q-groups, one atomic
  // per column per wave (256 adds per Vsum slot total).
  if (wn == 1) {
#pragma unroll
    for (int nt = 2; nt < 6; ++nt) {
      const int n = nbase + nt * 16 + ml;          // 128..191
      float s = acc[nt][0] + acc[nt][1] + acc[nt][2] + acc[nt][3] + 4.f * bv[n - 128];
      s += __shfl_xor(s, 16, 64);
      s += __shfl_xor(s, 32, 64);
      if (q == 0) atomicAdd(&Vsum[(r0 >> 12) * 64 + (n - 128)], s);
    }
  }
}

// ---------------------------------------------------------------------------
// Per-row scores + softmax-with-zero-background + V combine (faithful quirk).
// ---------------------------------------------------------------------------
__global__ __launch_bounds__(256) void attn_kernel(const float* __restrict__ C,
                                                   const float* __restrict__ Vsum,
                                                   float* __restrict__ out) {
  const int t    = threadIdx.x;
  const int lane = t & 63;
  const int wave = t >> 6;
  const int r = blockIdx.x * 4 + wave;
  const int b = r >> 12;
  const int i = r & (NTOK - 1);

  const float q  = C[(size_t)r * CN + lane];
  const float kc = C[(size_t)r * CN + 64 + lane];
  float km = 0.f, kp = 0.f;
  if (i > 0)        km = C[(size_t)(r - 1) * CN + 64 + lane];
  if (i < NTOK - 1) kp = C[(size_t)(r + 1) * CN + 64 + lane];

  float p0 = q * km, p1 = q * kc, p2 = q * kp;
#pragma unroll
  for (int off = 32; off > 0; off >>= 1) {
    p0 += __shfl_xor(p0, off, 64);
    p1 += __shfl_xor(p1, off, 64);
    p2 += __shfl_xor(p2, off, 64);
  }

  const float s0 = (i > 0) ? p0 : 0.f;
  const float s1 = p1;
  const float s2 = (i < NTOK - 1) ? p2 : 0.f;
  const float m  = fmaxf(fmaxf(s0, s1), fmaxf(s2, 0.f));
  const float e0 = expf(s0 - m);
  const float e1 = expf(s1 - m);
  const float e2 = expf(s2 - m);
  const float ez = expf(-m);
  const float Z  = e0 + e1 + e2 + (float)(NTOK - 3) * ez;

  const size_t vb = ((size_t)b * NTOK) * CN + 128;
  const float v0 = C[vb + lane];
  const float v1 = C[vb + CN + lane];
  const float v2 = C[vb + 2 * (size_t)CN + lane];
  const float vs = Vsum[b * 64 + lane];

  out[(size_t)r * 64 + lane] =
      (e0 * v0 + e1 * v1 + e2 * v2 + ez * (vs - v0 - v1 - v2)) / Z;
}

// ---------------------------------------------------------------------------
extern "C" void kernel_launch(void* const* d_in, const int* in_sizes, int n_in,
                              void* d_out, int out_size, void* d_ws, size_t ws_size,
                              hipStream_t stream) {
  const float* x  = (const float*)d_in[0];
  const float* Wq = (const float*)d_in[1];
  const float* bq = (const float*)d_in[2];
  const float* Wk = (const float*)d_in[3];
  const float* bk = (const float*)d_in[4];
  const float* Wv = (const float*)d_in[5];
  const float* bv = (const float*)d_in[6];
  float* out = (float*)d_out;

  float* C    = (float*)d_ws;                              // 16384 x 192 fp32 (12 MiB)
  float* Vsum = C + (size_t)ROWS * CN;                     // 4 x 64
  unsigned short* Wt = (unsigned short*)(Vsum + NB * 64);  // 24 x 2 x 192 x 32 bf16 (576 KiB)

  wprep<<<72, 256, 0, stream>>>(Wq, Wk, Wv, Wt, Vsum);
  qkv_mfma<<<512, 256, 0, stream>>>(x, Wt, bq, bk, bv, C, Vsum);
  attn_kernel<<<ROWS / 4, 256, 0, stream>>>(C, Vsum, out);
}

// Round 2
// 128.208 us; speedup vs baseline: 1.1602x; 1.1221x over previous
//
#include <hip/hip_runtime.h>
#include <math.h>

#define EMBED 768
#define NTOK  4096
#define NB    4
#define ROWS  16384          // 4 * 4096
#define CN    192            // Q(64)|K(64)|V(64)

typedef __attribute__((ext_vector_type(8))) short bf16x8;          // 8 bf16 = 4 VGPR
typedef __attribute__((ext_vector_type(8))) unsigned short u16x8;  // store vector
typedef __attribute__((ext_vector_type(4))) float f32x4;           // MFMA acc

// Split fp32 into h + l bf16 (RNE both, tie-parity exact): used in wprep.
__device__ inline void split2(float f, short& h, short& l) {
  union { float f; unsigned u; } a; a.f = f;
  unsigned r = (a.u + 0x7FFFu + ((a.u >> 16) & 1u)) & 0xFFFF0000u;
  h = (short)(r >> 16);
  union { unsigned u; float f; } hf; hf.u = r;
  union { float f; unsigned u; } b; b.f = f - hf.f;
  l = (short)((b.u + 0x7FFFu + ((b.u >> 16) & 1u)) >> 16);
}

// A-side split: RNE high plane (bit-identical to split2 h), round-up-at-half low
// plane (residual is exact by Sterbenz; lsb-tie handling is numerically moot).
__device__ inline void splitA(float f, short& h, short& l) {
  union { float f; unsigned u; } a; a.f = f;
  unsigned r = (a.u + 0x7FFFu + ((a.u >> 16) & 1u)) & 0xFFFF0000u;
  h = (short)(r >> 16);
  union { unsigned u; float f; } hf; hf.u = r;
  union { float f; unsigned u; } b; b.f = f - hf.f;
  l = (short)((b.u + 0x8000u) >> 16);
}

// ---------------------------------------------------------------------------
// W prep: LDS-staged transpose, coalesced both sides.
// Wt[ks][plane][n][k32] bf16: elem = ks*12288 + p*6144 + n*32 + kk.
// Per-ks slice (24576 B) is verbatim the LDS staging block for qkv.
// Also zeroes Vsum.
// ---------------------------------------------------------------------------
__global__ __launch_bounds__(256) void wprep(const float* __restrict__ Wq,
                                             const float* __restrict__ Wk,
                                             const float* __restrict__ Wv,
                                             unsigned short* __restrict__ Wt,
                                             float* __restrict__ Vsum) {
  __shared__ float tile[32 * 64];   // W[ks*32 .. +32][0..64]
  const int b   = blockIdx.x;
  const int mat = b / 24;           // 0=Wq 1=Wk 2=Wv
  const int ks  = b - mat * 24;
  const float* W = (mat == 0) ? Wq : (mat == 1) ? Wk : Wv;
  const int t = threadIdx.x;

  const float4* src = (const float4*)(W + ks * 2048);
  ((float4*)tile)[t]       = src[t];
  ((float4*)tile)[t + 256] = src[t + 256];
  __syncthreads();

  const int n  = t >> 2;            // 0..63
  const int ko = (t & 3) * 8;       // 0,8,16,24
  u16x8 hv, lv;
#pragma unroll
  for (int j = 0; j < 8; ++j) {
    short h, l;
    split2(tile[(ko + j) * 64 + n], h, l);
    hv[j] = (unsigned short)h;
    lv[j] = (unsigned short)l;
  }
  const size_t base = (size_t)ks * 12288 + (size_t)(mat * 64 + n) * 32 + ko;
  *(u16x8*)(Wt + base)        = hv;
  *(u16x8*)(Wt + base + 6144) = lv;

  if (b == 0 && t < NB * 64) Vsum[t] = 0.f;
}

// ---------------------------------------------------------------------------
// MFMA GEMM: C[16384][192] = x @ W + bias, split-bf16 (3 MFMA passes).
// 512 blocks x 256 threads (4 waves: 2m x 2n), block tile 32x192, wave 16x96.
// B staged global->LDS via global_load_lds (verbatim 24576-B slice, double
// buffered, one __syncthreads per k-step). B frags ds_read_b128'd immediately
// before use -> no register arrays anywhere (scratch-proof). A ping-pong in
// named float4s. Fused Vsum epilogue.
// ---------------------------------------------------------------------------
__device__ inline void gload_lds16(const unsigned short* g, unsigned short* l) {
  __builtin_amdgcn_global_load_lds(
      (const __attribute__((address_space(1))) unsigned int*)(g),
      (__attribute__((address_space(3))) unsigned int*)(l),
      16, 0, 0);
}

#define STAGE(LB, KS) do {                                            \
    const unsigned short* _g = Wtu + (size_t)(KS) * 12288 + tid * 8;  \
    unsigned short* _l = (LB) + tid * 8;                              \
    gload_lds16(_g,          _l);                                     \
    gload_lds16(_g + 2048,   _l + 2048);                              \
    gload_lds16(_g + 4096,   _l + 4096);                              \
    gload_lds16(_g + 6144,   _l + 6144);                              \
    gload_lds16(_g + 8192,   _l + 8192);                              \
    gload_lds16(_g + 10240,  _l + 10240);                             \
  } while (0)

#define DO_NT(LBP, NT, ACC) do {                                               \
    bf16x8 _bh = *(const bf16x8*)((LBP) + (NT) * 512);                         \
    bf16x8 _bl = *(const bf16x8*)((LBP) + (NT) * 512 + 6144);                  \
    ACC = __builtin_amdgcn_mfma_f32_16x16x32_bf16(ah, _bh, ACC, 0, 0, 0);      \
    ACC = __builtin_amdgcn_mfma_f32_16x16x32_bf16(ah, _bl, ACC, 0, 0, 0);      \
    ACC = __builtin_amdgcn_mfma_f32_16x16x32_bf16(al, _bh, ACC, 0, 0, 0);      \
  } while (0)

#define COMPUTE(LB, F0, F1) do {                                      \
    bf16x8 ah, al; short _h, _l;                                      \
    splitA((F0).x, _h, _l); ah[0] = _h; al[0] = _l;                   \
    splitA((F0).y, _h, _l); ah[1] = _h; al[1] = _l;                   \
    splitA((F0).z, _h, _l); ah[2] = _h; al[2] = _l;                   \
    splitA((F0).w, _h, _l); ah[3] = _h; al[3] = _l;                   \
    splitA((F1).x, _h, _l); ah[4] = _h; al[4] = _l;                   \
    splitA((F1).y, _h, _l); ah[5] = _h; al[5] = _l;                   \
    splitA((F1).z, _h, _l); ah[6] = _h; al[6] = _l;                   \
    splitA((F1).w, _h, _l); ah[7] = _h; al[7] = _l;                   \
    const unsigned short* _lb = (LB) + lboff;                         \
    DO_NT(_lb, 0, acc0); DO_NT(_lb, 1, acc1); DO_NT(_lb, 2, acc2);    \
    DO_NT(_lb, 3, acc3); DO_NT(_lb, 4, acc4); DO_NT(_lb, 5, acc5);    \
  } while (0)

__global__ __launch_bounds__(256, 2) void qkv_mfma(const float* __restrict__ x,
                                                   const unsigned short* __restrict__ Wtu,
                                                   const float* __restrict__ bq,
                                                   const float* __restrict__ bk,
                                                   const float* __restrict__ bv,
                                                   float* __restrict__ C,
                                                   float* __restrict__ Vsum) {
  __shared__ unsigned short lbuf0[12288];   // 24576 B, ks even
  __shared__ unsigned short lbuf1[12288];   // 24576 B, ks odd

  const int tid   = threadIdx.x;
  const int lane  = tid & 63;
  const int wm    = (tid >> 6) & 1;   // m-half (16 rows)
  const int wn    = tid >> 7;         // n-half (96 cols)
  const int ml    = lane & 15;
  const int q     = lane >> 4;
  const int r0    = blockIdx.x * 32;
  const int nbase = wn * 96;
  // LDS frag base (shorts): n = wn*96 + ml, +k-oct q
  const int lboff = (wn * 96 + ml) * 32 + q * 8;

  f32x4 acc0 = {0.f, 0.f, 0.f, 0.f}, acc1 = {0.f, 0.f, 0.f, 0.f},
        acc2 = {0.f, 0.f, 0.f, 0.f}, acc3 = {0.f, 0.f, 0.f, 0.f},
        acc4 = {0.f, 0.f, 0.f, 0.f}, acc5 = {0.f, 0.f, 0.f, 0.f};

  const float* xap = x + (size_t)(r0 + wm * 16 + ml) * EMBED + q * 8;

  // prologue: stage ks=0, load A(ks=0)
  STAGE(lbuf0, 0);
  float4 a0 = *(const float4*)xap;
  float4 a1 = *(const float4*)(xap + 4);

  for (int ks = 0; ks < 24; ks += 2) {
    // ---- even step: compute lbuf0, stage ks+1 -> lbuf1 ----
    __syncthreads();                       // staging of lbuf0 drained (vmcnt0)
    STAGE(lbuf1, ks + 1);                  // safe: prev reads of lbuf1 pre-barrier
    float4 n0 = *(const float4*)(xap + 32);   // A(ks+1)
    float4 n1 = *(const float4*)(xap + 36);
    COMPUTE(lbuf0, a0, a1);

    // ---- odd step: compute lbuf1, stage ks+2 -> lbuf0 ----
    __syncthreads();
    if (ks < 22) {
      STAGE(lbuf0, ks + 2);
      float4 m0 = *(const float4*)(xap + 64);  // A(ks+2)
      float4 m1 = *(const float4*)(xap + 68);
      a0 = m0; a1 = m1;
    }
    COMPUTE(lbuf1, n0, n1);
    xap += 64;
  }

  // epilogue: bias + store. C/D layout: col = ml, row = q*4 + reg.
#define EPI(NT, ACC) do {                                                   \
    const int n = nbase + (NT) * 16 + ml;                                   \
    const float bias = (n < 64) ? bq[n] : (n < 128) ? bk[n - 64] : bv[n - 128]; \
    const int row = r0 + wm * 16 + q * 4;                                   \
    C[(size_t)(row + 0) * CN + n] = ACC[0] + bias;                          \
    C[(size_t)(row + 1) * CN + n] = ACC[1] + bias;                          \
    C[(size_t)(row + 2) * CN + n] = ACC[2] + bias;                          \
    C[(size_t)(row + 3) * CN + n] = ACC[3] + bias;                          \
  } while (0)

  EPI(0, acc0); EPI(1, acc1); EPI(2, acc2);
  EPI(3, acc3); EPI(4, acc4); EPI(5, acc5);

  // fused Vsum partials: V cols (n>=128) live in wn==1, nt>=2.
#define VS(NT, ACC) do {                                                    \
    const int n = nbase + (NT) * 16 + ml;                                   \
    float s = ACC[0] + ACC[1] + ACC[2] + ACC[3] + 4.f * bv[n - 128];        \
    s += __shfl_xor(s, 16, 64);                                             \
    s += __shfl_xor(s, 32, 64);                                             \
    if (q == 0) atomicAdd(&Vsum[(r0 >> 12) * 64 + (n - 128)], s);           \
  } while (0)

  if (wn == 1) {
    VS(2, acc2); VS(3, acc3); VS(4, acc4); VS(5, acc5);
  }
}

// ---------------------------------------------------------------------------
// Per-row scores + softmax-with-zero-background + V combine (faithful quirk).
// ---------------------------------------------------------------------------
__global__ __launch_bounds__(256) void attn_kernel(const float* __restrict__ C,
                                                   const float* __restrict__ Vsum,
                                                   float* __restrict__ out) {
  const int t    = threadIdx.x;
  const int lane = t & 63;
  const int wave = t >> 6;
  const int r = blockIdx.x * 4 + wave;
  const int b = r >> 12;
  const int i = r & (NTOK - 1);

  const float q  = C[(size_t)r * CN + lane];
  const float kc = C[(size_t)r * CN + 64 + lane];
  float km = 0.f, kp = 0.f;
  if (i > 0)        km = C[(size_t)(r - 1) * CN + 64 + lane];
  if (i < NTOK - 1) kp = C[(size_t)(r + 1) * CN + 64 + lane];

  float p0 = q * km, p1 = q * kc, p2 = q * kp;
#pragma unroll
  for (int off = 32; off > 0; off >>= 1) {
    p0 += __shfl_xor(p0, off, 64);
    p1 += __shfl_xor(p1, off, 64);
    p2 += __shfl_xor(p2, off, 64);
  }

  const float s0 = (i > 0) ? p0 : 0.f;
  const float s1 = p1;
  const float s2 = (i < NTOK - 1) ? p2 : 0.f;
  const float m  = fmaxf(fmaxf(s0, s1), fmaxf(s2, 0.f));
  const float e0 = expf(s0 - m);
  const float e1 = expf(s1 - m);
  const float e2 = expf(s2 - m);
  const float ez = expf(-m);
  const float Z  = e0 + e1 + e2 + (float)(NTOK - 3) * ez;

  const size_t vb = ((size_t)b * NTOK) * CN + 128;
  const float v0 = C[vb + lane];
  const float v1 = C[vb + CN + lane];
  const float v2 = C[vb + 2 * (size_t)CN + lane];
  const float vs = Vsum[b * 64 + lane];

  out[(size_t)r * 64 + lane] =
      (e0 * v0 + e1 * v1 + e2 * v2 + ez * (vs - v0 - v1 - v2)) / Z;
}

// ---------------------------------------------------------------------------
extern "C" void kernel_launch(void* const* d_in, const int* in_sizes, int n_in,
                              void* d_out, int out_size, void* d_ws, size_t ws_size,
                              hipStream_t stream) {
  const float* x  = (const float*)d_in[0];
  const float* Wq = (const float*)d_in[1];
  const float* bq = (const float*)d_in[2];
  const float* Wk = (const float*)d_in[3];
  const float* bk = (const float*)d_in[4];
  const float* Wv = (const float*)d_in[5];
  const float* bv = (const float*)d_in[6];
  float* out = (float*)d_out;

  float* C    = (float*)d_ws;                              // 16384 x 192 fp32 (12 MiB)
  float* Vsum = C + (size_t)ROWS * CN;                     // 4 x 64
  unsigned short* Wt = (unsigned short*)(Vsum + NB * 64);  // 24 x 2 x 192 x 32 bf16 (576 KiB)

  wprep<<<72, 256, 0, stream>>>(Wq, Wk, Wv, Wt, Vsum);
  qkv_mfma<<<512, 256, 0, stream>>>(x, Wt, bq, bk, bv, C, Vsum);
  attn_kernel<<<ROWS / 4, 256, 0, stream>>>(C, Vsum, out);
}